// Round 1
// baseline (300.768 us; speedup 1.0000x reference)
//
#include <hip/hip_runtime.h>

// MoE RT-DETR FFN on MI355X.
// E=6, D=256, H=256, TOP_K=2, ROUTER_H=128, tokens N=8*4096=32768.
// Strategy: fp32 router (selection exactness) -> per-expert token gather ->
// grouped fp16-MFMA GEMM over selected (token,expert) pairs only (3x FLOP cut
// vs dense reference) -> atomicAdd combine (2 adds/address, order-invariant).

#define N_TOK 32768
#define E_EXP 6

typedef _Float16 f16x8 __attribute__((ext_vector_type(8)));
typedef float    f32x4 __attribute__((ext_vector_type(4)));
typedef unsigned int u32x4 __attribute__((ext_vector_type(4)));

// ws layout (bytes):
//   [0,256)                      : counts[6] (zeroed by memset)
//   [256, 256+786432)            : list  [6][32768] int   (token ids)
//   [786688, 786688+786432)      : wlist [6][32768] float (routing weights)
//   [1573120, 1573120+2949120)   : wt fp16 [e][l][kt][n=256][40]  (padded LDS tile images)
#define WS_LIST  256
#define WS_WLIST (256 + 786432)
#define WS_WT    (256 + 2 * 786432)

__device__ __forceinline__ unsigned pack_f16x2(float x, float y) {
  unsigned short a = __builtin_bit_cast(unsigned short, (_Float16)x);
  unsigned short b = __builtin_bit_cast(unsigned short, (_Float16)y);
  return (unsigned)a | ((unsigned)b << 16);
}

// async global->LDS, 16B per lane. LDS dst must be wave-uniform base + lane*16.
__device__ __forceinline__ void async_cp16(const void* g, void* l) {
  __builtin_amdgcn_global_load_lds(
      (__attribute__((address_space(1))) void*)(void*)(g),
      (__attribute__((address_space(3))) void*)(l),
      16, 0, 0);
}

// ---------------------------------------------------------------------------
// K1: convert expert weights fp32 [E][256][256] (k-major) into fp16 transposed
// padded tile images: wt[((e*3+l)*8+kt)] = [n=256][kk=40 (32 used + 8 pad)],
// wt[...][n][kk] = W[e][kt*32+kk][n].  One block per (e,l,kt) tile.
// ---------------------------------------------------------------------------
__global__ __launch_bounds__(256) void convert_w_kernel(
    const float* __restrict__ w1, const float* __restrict__ w2,
    const float* __restrict__ w3, _Float16* __restrict__ wt) {
  int blk = blockIdx.x;              // 144 = 6*3*8
  int kt  = blk & 7;
  int el  = blk >> 3;
  int l   = el % 3;
  int e   = el / 3;
  const float* W = (l == 0 ? w1 : (l == 1 ? w2 : w3)) + (size_t)e * 65536;
  int n = threadIdx.x;               // 0..255
  _Float16* dst = wt + (size_t)blk * 10240 + n * 40;
  #pragma unroll
  for (int j = 0; j < 4; ++j) {
    u32x4 v;
    #pragma unroll
    for (int i = 0; i < 4; ++i) {
      float x = W[(size_t)(kt * 32 + j * 8 + i * 2) * 256 + n];
      float y = W[(size_t)(kt * 32 + j * 8 + i * 2 + 1) * 256 + n];
      v[i] = pack_f16x2(x, y);
    }
    *(u32x4*)(dst + j * 8) = v;
  }
}

// ---------------------------------------------------------------------------
// K2: router. 32 tokens/block, 128 threads (thread = hidden unit h).
// fp32 throughout. Top-2 + renorm softmax, block-aggregated scatter into
// per-expert lists.
// ---------------------------------------------------------------------------
__global__ __launch_bounds__(128) void router_kernel(
    const float* __restrict__ feat, const float* __restrict__ rw1,
    const float* __restrict__ rb1, const float* __restrict__ rw2,
    const float* __restrict__ rb2, int* __restrict__ counts,
    int* __restrict__ list, float* __restrict__ wlist) {
  __shared__ __align__(16) float xs[32 * 256];
  __shared__ float rh[32 * 128];
  __shared__ float lg[32 * 6];
  __shared__ int   lcnt[E_EXP];
  __shared__ int   gbase[E_EXP];
  int tid  = threadIdx.x;
  int tok0 = blockIdx.x * 32;

  // stage 32 token rows (coalesced float4)
  const float4* src = (const float4*)(feat + (size_t)tok0 * 256);
  float4* xs4 = (float4*)xs;
  #pragma unroll
  for (int j = 0; j < 16; ++j) xs4[j * 128 + tid] = src[j * 128 + tid];
  if (tid < E_EXP) lcnt[tid] = 0;
  __syncthreads();

  // layer 1: rh[t][tid] = relu(x[t] . rw1[:,tid] + rb1[tid])
  float acc[32];
  {
    float b = rb1[tid];
    #pragma unroll
    for (int t = 0; t < 32; ++t) acc[t] = b;
  }
  for (int d4 = 0; d4 < 64; ++d4) {           // d in chunks of 4
    float w0 = rw1[(d4 * 4 + 0) * 128 + tid];
    float w1v = rw1[(d4 * 4 + 1) * 128 + tid];
    float w2v = rw1[(d4 * 4 + 2) * 128 + tid];
    float w3v = rw1[(d4 * 4 + 3) * 128 + tid];
    #pragma unroll
    for (int t = 0; t < 32; ++t) {
      float4 x = xs4[t * 64 + d4];            // LDS broadcast (same addr all lanes)
      acc[t] = fmaf(x.w, w3v, fmaf(x.z, w2v, fmaf(x.y, w1v, fmaf(x.x, w0, acc[t]))));
    }
  }
  #pragma unroll
  for (int t = 0; t < 32; ++t) rh[t * 128 + tid] = fmaxf(acc[t], 0.f);
  __syncthreads();

  // layer 2: logits [32][6]
  for (int it = tid; it < 32 * E_EXP; it += 128) {
    int t = it / E_EXP, ei = it % E_EXP;
    float s = rb2[ei];
    for (int h = 0; h < 128; ++h) s += rh[t * 128 + h] * rw2[h * E_EXP + ei];
    lg[t * E_EXP + ei] = s;
  }
  __syncthreads();

  // softmax -> top2 -> renorm softmax -> local scatter
  int sel0 = 0, sel1 = 0, loc0 = 0, loc1 = 0, token = 0;
  float sw0 = 0.f, sw1 = 0.f;
  if (tid < 32) {
    token = tok0 + tid;
    float p[E_EXP];
    float mx = -1e30f;
    #pragma unroll
    for (int i = 0; i < E_EXP; ++i) { p[i] = lg[tid * E_EXP + i]; mx = fmaxf(mx, p[i]); }
    float sum = 0.f;
    #pragma unroll
    for (int i = 0; i < E_EXP; ++i) { p[i] = expf(p[i] - mx); sum += p[i]; }
    float inv = 1.f / sum;
    #pragma unroll
    for (int i = 0; i < E_EXP; ++i) p[i] *= inv;
    float b1v = p[0]; sel0 = 0;
    #pragma unroll
    for (int i = 1; i < E_EXP; ++i) if (p[i] > b1v) { b1v = p[i]; sel0 = i; }
    float b2v = -1.f; sel1 = 0;
    #pragma unroll
    for (int i = 0; i < E_EXP; ++i)
      if (i != sel0 && p[i] > b2v) { b2v = p[i]; sel1 = i; }
    // softmax over the two top PROBABILITIES (b1v >= b2v)
    float r = expf(b2v - b1v);
    sw0 = 1.f / (1.f + r);
    sw1 = r / (1.f + r);
    loc0 = atomicAdd(&lcnt[sel0], 1);
    loc1 = atomicAdd(&lcnt[sel1], 1);
  }
  __syncthreads();
  if (tid < E_EXP) gbase[tid] = atomicAdd(&counts[tid], lcnt[tid]);
  __syncthreads();
  if (tid < 32) {
    int p0 = gbase[sel0] + loc0;
    list[sel0 * N_TOK + p0]  = token;
    wlist[sel0 * N_TOK + p0] = sw0;
    int p1 = gbase[sel1] + loc1;
    list[sel1 * N_TOK + p1]  = token;
    wlist[sel1 * N_TOK + p1] = sw1;
  }
}

// ---------------------------------------------------------------------------
// K3: grouped GEMM over selected (token,expert) pairs.
// Block = 256 threads (4 waves, 2x2: token-half x col-half), 32 tokens/block.
// 3 chained layers of [32,256]@[256,256] via mfma_f32_16x16x32_f16,
// A in LDS [32][264] fp16 (pad 8), B double-buffered [256][40] fp16 tiles
// streamed with global_load_lds from pre-converted ws images.
// ---------------------------------------------------------------------------
__global__ __launch_bounds__(256) void expert_kernel(
    const float* __restrict__ feat, const _Float16* __restrict__ wt,
    const float* __restrict__ eb1, const float* __restrict__ eb2,
    const float* __restrict__ eb3, const int* __restrict__ counts,
    const int* __restrict__ list, const float* __restrict__ wlist,
    float* __restrict__ out) {
  __shared__ __align__(16) _Float16 Ah[32 * 264];
  __shared__ __align__(16) _Float16 Bh[2][256 * 40];
  __shared__ int   toks[32];
  __shared__ float wgts[32];

  int e    = blockIdx.y;
  int tile = blockIdx.x;
  int cnt  = counts[e];
  int base = tile * 32;
  if (base >= cnt) return;

  int tid = threadIdx.x;
  if (tid < 32) {
    int idx = base + tid;
    int tk = 0; float w = 0.f;
    if (idx < cnt) { tk = list[e * N_TOK + idx]; w = wlist[e * N_TOK + idx]; }
    toks[tid] = tk;
    wgts[tid] = w;                 // w==0 rows contribute exact 0 via atomicAdd
  }
  __syncthreads();

  // stage A (layer-1 input): gather token rows, cvt fp32->fp16
  {
    int r = tid >> 3, seg = tid & 7;
    const float4* srcr = (const float4*)(feat + (size_t)toks[r] * 256 + seg * 32);
    _Float16* drow = &Ah[r * 264 + seg * 32];
    #pragma unroll
    for (int j = 0; j < 4; ++j) {
      float4 a = srcr[2 * j], b = srcr[2 * j + 1];
      u32x4 pk;
      pk[0] = pack_f16x2(a.x, a.y);
      pk[1] = pack_f16x2(a.z, a.w);
      pk[2] = pack_f16x2(b.x, b.y);
      pk[3] = pack_f16x2(b.z, b.w);
      *(u32x4*)(drow + j * 8) = pk;
    }
  }

  auto stageB = [&](int l, int kt, _Float16* dst) {
    const _Float16* src = wt + (size_t)((e * 3 + l) * 8 + kt) * 10240;
    #pragma unroll
    for (int j = 0; j < 5; ++j) {          // 20 KB = 1280 lanes * 16 B
      int c = j * 256 + tid;               // per (wave,j): base + lane*16  (uniform)
      async_cp16(src + c * 8, dst + c * 8);
    }
  };
  stageB(0, 0, Bh[0]);

  int wv = tid >> 6, lane = tid & 63;
  int th = wv >> 1, chh = wv & 1;          // token half / col half
  int mm = lane & 15, qq = lane >> 4;
  int arow = th * 16 + mm;
  const float* biases[3] = {eb1 + e * 256, eb2 + e * 256, eb3 + e * 256};

  int tk4[4]; float wg4[4];

  f32x4 acc[8];
  for (int l = 0; l < 3; ++l) {
    const float* bp = biases[l];
    #pragma unroll
    for (int nt = 0; nt < 8; ++nt) {
      float bv = bp[chh * 128 + nt * 16 + mm];
      acc[nt][0] = bv; acc[nt][1] = bv; acc[nt][2] = bv; acc[nt][3] = bv;
    }
    for (int kt = 0; kt < 8; ++kt) {
      __syncthreads();                     // B[kt&1] ready; A ready
      if (kt < 7)       stageB(l, kt + 1, Bh[(kt + 1) & 1]);
      else if (l < 2)   stageB(l + 1, 0, Bh[0]);
      f16x8 a = *(const f16x8*)&Ah[arow * 264 + kt * 32 + qq * 8];
      #pragma unroll
      for (int nt = 0; nt < 8; ++nt) {
        f16x8 b = *(const f16x8*)&Bh[kt & 1][(chh * 128 + nt * 16 + mm) * 40 + qq * 8];
        acc[nt] = __builtin_amdgcn_mfma_f32_16x16x32_f16(a, b, acc[nt], 0, 0, 0);
      }
    }
    __syncthreads();                       // all reads of A done before overwrite
    if (l < 2) {
      #pragma unroll
      for (int nt = 0; nt < 8; ++nt) {
        int ncol = chh * 128 + nt * 16 + mm;
        #pragma unroll
        for (int r = 0; r < 4; ++r) {
          int row = th * 16 + qq * 4 + r;  // C/D: row = quad*4 + reg, col = lane&15
          Ah[row * 264 + ncol] = (_Float16)fmaxf(acc[nt][r], 0.f);
        }
      }
    } else {
      #pragma unroll
      for (int r = 0; r < 4; ++r) {
        int row = th * 16 + qq * 4 + r;
        tk4[r] = toks[row];
        wg4[r] = wgts[row];
      }
      #pragma unroll
      for (int nt = 0; nt < 8; ++nt) {
        int ncol = chh * 128 + nt * 16 + mm;
        #pragma unroll
        for (int r = 0; r < 4; ++r) {
          atomicAdd(&out[(size_t)tk4[r] * 256 + ncol], acc[nt][r] * wg4[r]);
        }
      }
    }
  }
}

extern "C" void kernel_launch(void* const* d_in, const int* in_sizes, int n_in,
                              void* d_out, int out_size, void* d_ws, size_t ws_size,
                              hipStream_t stream) {
  const float* feat = (const float*)d_in[0];
  const float* rw1  = (const float*)d_in[1];
  const float* rb1  = (const float*)d_in[2];
  const float* rw2  = (const float*)d_in[3];
  const float* rb2  = (const float*)d_in[4];
  const float* ew1  = (const float*)d_in[5];
  const float* eb1  = (const float*)d_in[6];
  const float* ew2  = (const float*)d_in[7];
  const float* eb2  = (const float*)d_in[8];
  const float* ew3  = (const float*)d_in[9];
  const float* eb3  = (const float*)d_in[10];
  float* out = (float*)d_out;

  char* ws = (char*)d_ws;
  int*      counts = (int*)(ws);
  int*      list   = (int*)(ws + WS_LIST);
  float*    wlist  = (float*)(ws + WS_WLIST);
  _Float16* wt     = (_Float16*)(ws + WS_WT);

  hipMemsetAsync(ws, 0, 256, stream);                                  // counts
  hipMemsetAsync(d_out, 0, (size_t)out_size * sizeof(float), stream);  // atomic target

  convert_w_kernel<<<144, 256, 0, stream>>>(ew1, ew2, ew3, wt);
  router_kernel<<<N_TOK / 32, 128, 0, stream>>>(feat, rw1, rb1, rw2, rb2,
                                                counts, list, wlist);
  expert_kernel<<<dim3(N_TOK / 32, E_EXP), 256, 0, stream>>>(
      feat, wt, eb1, eb2, eb3, counts, list, wlist, out);
}

// Round 2
// 292.558 us; speedup vs baseline: 1.0281x; 1.0281x over previous
//
#include <hip/hip_runtime.h>

// MoE RT-DETR FFN on MI355X (gfx950).
// E=6, D=256, H=256, TOP_K=2, ROUTER_H=128, tokens N=8*4096=32768.
// fp32 router (selection exactness) -> per-expert gather -> grouped fp16-MFMA
// GEMM over selected pairs only (3x FLOP cut) -> atomicAdd combine.
//
// Round 2: expert kernel rebuilt: M=64 tokens/block, 4 waves each owning a
// 64x64 register tile (4x4 of 16x16x32 f16 MFMA). All LDS in fragment order
// (lane*16 contiguous) = global_load_lds-compatible + bank-conflict floor.
// A tile uses an XOR (m^g) swizzle so the C->A layer-boundary writeback is
// conflict-free (16 distinct bank pairs per store instruction).

#define N_TOK 32768
#define E_EXP 6

typedef _Float16 f16x8 __attribute__((ext_vector_type(8)));
typedef _Float16 f16x4 __attribute__((ext_vector_type(4)));
typedef float    f32x4 __attribute__((ext_vector_type(4)));
typedef unsigned int u32x4 __attribute__((ext_vector_type(4)));

// ws layout (bytes):
//   [0,256)              counts[6]
//   [256, +786432)       list  [6][32768] int
//   [+786432, +786432)   wlist [6][32768] float
//   [WS_WT, +2359296)    wt fp16 [e][l][kt=8][ct=16][slot=64][8]  (frag order)
#define WS_LIST  256
#define WS_WLIST (256 + 786432)
#define WS_WT    (256 + 2 * 786432)

__device__ __forceinline__ unsigned pack_f16x2(float x, float y) {
  unsigned short a = __builtin_bit_cast(unsigned short, (_Float16)x);
  unsigned short b = __builtin_bit_cast(unsigned short, (_Float16)y);
  return (unsigned)a | ((unsigned)b << 16);
}

// async global->LDS, 16B/lane; LDS dst = wave-uniform base + lane*16.
__device__ __forceinline__ void async_cp16(const void* g, void* l) {
  __builtin_amdgcn_global_load_lds(
      (__attribute__((address_space(1))) void*)(void*)(g),
      (__attribute__((address_space(3))) void*)(l),
      16, 0, 0);
}

// A-fragment LDS addressing (swizzled), element (row-tile rt, m=row&15, k):
//   block (kt=k>>5, rt) of 1024 B; g = (k&31)>>2 (0..7); byte =
//   block*1024 + ((g<<4) | (m^g))*8 + (k&3)*2
__device__ __forceinline__ int a_off(int kt, int rt, int m, int kl) {
  int g = kl >> 2;
  return (((kt << 2) | rt) << 10) + (((g << 4) | (m ^ g)) << 3) + ((kl & 3) << 1);
}

// ---------------------------------------------------------------------------
// K1: convert expert weights fp32 [E][256][256] (k-major) -> fp16 B images in
// exact MFMA fragment order: img[(e*3+l)][kt][ct][slot L][j] = W[kt*32 +
// (L>>4)*8 + j][ct*16 + (L&15)].  One block per (e,l,kt): 144 blocks.
// ---------------------------------------------------------------------------
__global__ __launch_bounds__(256) void convert_w_kernel(
    const float* __restrict__ w1, const float* __restrict__ w2,
    const float* __restrict__ w3, _Float16* __restrict__ wt) {
  __shared__ __align__(16) float xs[32 * 256];
  int blk = blockIdx.x;               // 144 = 6*3*8
  int kt = blk & 7, el = blk >> 3, l = el % 3, e = el / 3;
  const float* W = (l == 0 ? w1 : (l == 1 ? w2 : w3)) +
                   (size_t)e * 65536 + (size_t)kt * 32 * 256;
  int t = threadIdx.x;
  float4* xs4 = (float4*)xs;
  const float4* src4 = (const float4*)W;
  #pragma unroll
  for (int j = 0; j < 8; ++j) xs4[j * 256 + t] = src4[j * 256 + t];
  __syncthreads();
  _Float16* dstb = wt + (size_t)((e * 3 + l) * 8 + kt) * 8192;
  #pragma unroll
  for (int si = 0; si < 4; ++si) {
    int s = t * 4 + si;               // slot index within kt image (0..1023)
    int ct = s >> 6, L = s & 63;
    int n = ct * 16 + (L & 15), kq = L >> 4;
    u32x4 pk;
    #pragma unroll
    for (int i = 0; i < 4; ++i) {
      float x = xs[(kq * 8 + 2 * i) * 256 + n];
      float y = xs[(kq * 8 + 2 * i + 1) * 256 + n];
      pk[i] = pack_f16x2(x, y);
    }
    *(u32x4*)(dstb + s * 8) = pk;
  }
}

// ---------------------------------------------------------------------------
// K2: router (unchanged from round 1; fp32 for selection exactness).
// ---------------------------------------------------------------------------
__global__ __launch_bounds__(128) void router_kernel(
    const float* __restrict__ feat, const float* __restrict__ rw1,
    const float* __restrict__ rb1, const float* __restrict__ rw2,
    const float* __restrict__ rb2, int* __restrict__ counts,
    int* __restrict__ list, float* __restrict__ wlist) {
  __shared__ __align__(16) float xs[32 * 256];
  __shared__ float rh[32 * 128];
  __shared__ float lg[32 * 6];
  __shared__ int   lcnt[E_EXP];
  __shared__ int   gbase[E_EXP];
  int tid  = threadIdx.x;
  int tok0 = blockIdx.x * 32;

  const float4* src = (const float4*)(feat + (size_t)tok0 * 256);
  float4* xs4 = (float4*)xs;
  #pragma unroll
  for (int j = 0; j < 16; ++j) xs4[j * 128 + tid] = src[j * 128 + tid];
  if (tid < E_EXP) lcnt[tid] = 0;
  __syncthreads();

  float acc[32];
  {
    float b = rb1[tid];
    #pragma unroll
    for (int t = 0; t < 32; ++t) acc[t] = b;
  }
  for (int d4 = 0; d4 < 64; ++d4) {
    float w0 = rw1[(d4 * 4 + 0) * 128 + tid];
    float w1v = rw1[(d4 * 4 + 1) * 128 + tid];
    float w2v = rw1[(d4 * 4 + 2) * 128 + tid];
    float w3v = rw1[(d4 * 4 + 3) * 128 + tid];
    #pragma unroll
    for (int t = 0; t < 32; ++t) {
      float4 x = xs4[t * 64 + d4];
      acc[t] = fmaf(x.w, w3v, fmaf(x.z, w2v, fmaf(x.y, w1v, fmaf(x.x, w0, acc[t]))));
    }
  }
  #pragma unroll
  for (int t = 0; t < 32; ++t) rh[t * 128 + tid] = fmaxf(acc[t], 0.f);
  __syncthreads();

  for (int it = tid; it < 32 * E_EXP; it += 128) {
    int t = it / E_EXP, ei = it % E_EXP;
    float s = rb2[ei];
    for (int h = 0; h < 128; ++h) s += rh[t * 128 + h] * rw2[h * E_EXP + ei];
    lg[t * E_EXP + ei] = s;
  }
  __syncthreads();

  int sel0 = 0, sel1 = 0, loc0 = 0, loc1 = 0, token = 0;
  float sw0 = 0.f, sw1 = 0.f;
  if (tid < 32) {
    token = tok0 + tid;
    float p[E_EXP];
    float mx = -1e30f;
    #pragma unroll
    for (int i = 0; i < E_EXP; ++i) { p[i] = lg[tid * E_EXP + i]; mx = fmaxf(mx, p[i]); }
    float sum = 0.f;
    #pragma unroll
    for (int i = 0; i < E_EXP; ++i) { p[i] = expf(p[i] - mx); sum += p[i]; }
    float inv = 1.f / sum;
    #pragma unroll
    for (int i = 0; i < E_EXP; ++i) p[i] *= inv;
    float b1v = p[0]; sel0 = 0;
    #pragma unroll
    for (int i = 1; i < E_EXP; ++i) if (p[i] > b1v) { b1v = p[i]; sel0 = i; }
    float b2v = -1.f; sel1 = 0;
    #pragma unroll
    for (int i = 0; i < E_EXP; ++i)
      if (i != sel0 && p[i] > b2v) { b2v = p[i]; sel1 = i; }
    float r = expf(b2v - b1v);
    sw0 = 1.f / (1.f + r);
    sw1 = r / (1.f + r);
    loc0 = atomicAdd(&lcnt[sel0], 1);
    loc1 = atomicAdd(&lcnt[sel1], 1);
  }
  __syncthreads();
  if (tid < E_EXP) gbase[tid] = atomicAdd(&counts[tid], lcnt[tid]);
  __syncthreads();
  if (tid < 32) {
    int p0 = gbase[sel0] + loc0;
    list[sel0 * N_TOK + p0]  = token;
    wlist[sel0 * N_TOK + p0] = sw0;
    int p1 = gbase[sel1] + loc1;
    list[sel1 * N_TOK + p1]  = token;
    wlist[sel1 * N_TOK + p1] = sw1;
  }
}

// ---------------------------------------------------------------------------
// K3: grouped GEMM. Block = 256 threads (4 waves), M=64 tokens, N=256.
// Wave w owns cols [w*64, w*64+64): 4x4 tiles of 16x16x32 f16 MFMA.
// A: 32 KB swizzled frag LDS (chained across 3 layers). B: 2x16 KB frag-order
// double buffer streamed via global_load_lds from pre-converted images.
// ---------------------------------------------------------------------------
__global__ __launch_bounds__(256, 2) void expert_kernel(
    const float* __restrict__ feat, const _Float16* __restrict__ wt,
    const float* __restrict__ eb1, const float* __restrict__ eb2,
    const float* __restrict__ eb3, const int* __restrict__ counts,
    const int* __restrict__ list, const float* __restrict__ wlist,
    float* __restrict__ out) {
  __shared__ __align__(16) _Float16 Ah[16384];     // 32 KB
  __shared__ __align__(16) _Float16 Bh[2][8192];   // 2 x 16 KB
  __shared__ int   toks[64];
  __shared__ float wgts[64];

  int e    = blockIdx.y;
  int tile = blockIdx.x;
  int cnt  = counts[e];
  int base = tile * 64;
  if (base >= cnt) return;

  int tid = threadIdx.x;
  if (tid < 64) {
    int idx = base + tid;
    int tk = 0; float w = 0.f;
    if (idx < cnt) { tk = list[e * N_TOK + idx]; w = wlist[e * N_TOK + idx]; }
    toks[tid] = tk;
    wgts[tid] = w;                  // w==0 rows add exact 0
  }
  __syncthreads();

  char* AhB = (char*)Ah;

  // stage A (layer-1 input): gather token rows fp32 -> fp16 swizzled frags
  {
    int row = tid >> 2, c4 = tid & 3;
    const float* srcr = feat + (size_t)toks[row] * 256;
    int rt = row >> 4, m = row & 15;
    #pragma unroll
    for (int i = 0; i < 16; ++i) {
      int k = i * 16 + c4 * 4;
      float4 v = *(const float4*)(srcr + k);
      uint2 pk;
      pk.x = pack_f16x2(v.x, v.y);
      pk.y = pack_f16x2(v.z, v.w);
      *(uint2*)(AhB + a_off(k >> 5, rt, m, k & 31)) = pk;
    }
  }

  auto stageB = [&](int l, int kt, _Float16* dst) {
    const _Float16* src = wt + (size_t)((e * 3 + l) * 8 + kt) * 8192;
    #pragma unroll
    for (int j = 0; j < 4; ++j) {   // 16 KB = 1024 lanes * 16 B
      int c = j * 256 + tid;
      async_cp16(src + c * 8, dst + c * 8);
    }
  };
  stageB(0, 0, Bh[0]);

  int wv = tid >> 6, L = tid & 63;
  int m = L & 15, q = L >> 4;       // a/b frag coords; k-slice = q*8
  int wcol = wv * 64;
  const float* biases[3] = {eb1 + e * 256, eb2 + e * 256, eb3 + e * 256};

  f32x4 acc[4][4];                  // [rt][ct]
  for (int l = 0; l < 3; ++l) {
    const float* bp = biases[l];
    #pragma unroll
    for (int ct = 0; ct < 4; ++ct) {
      float bv = bp[wcol + ct * 16 + m];
      #pragma unroll
      for (int rt = 0; rt < 4; ++rt) {
        acc[rt][ct][0] = bv; acc[rt][ct][1] = bv;
        acc[rt][ct][2] = bv; acc[rt][ct][3] = bv;
      }
    }
    for (int kt = 0; kt < 8; ++kt) {
      __syncthreads();              // B[kt&1] staged; A ready
      if (kt < 7)     stageB(l, kt + 1, Bh[(kt + 1) & 1]);
      else if (l < 2) stageB(l + 1, 0, Bh[0]);
      const _Float16* Bb = Bh[kt & 1];
      f16x8 bf[4];
      #pragma unroll
      for (int ct = 0; ct < 4; ++ct)
        bf[ct] = *(const f16x8*)(Bb + ((wv * 4 + ct) * 64 + L) * 8);
      f16x8 af[4];
      #pragma unroll
      for (int rt = 0; rt < 4; ++rt) {
        f16x4 lo = *(const f16x4*)(AhB + a_off(kt, rt, m, q * 8));
        f16x4 hi = *(const f16x4*)(AhB + a_off(kt, rt, m, q * 8 + 4));
        af[rt] = __builtin_shufflevector(lo, hi, 0, 1, 2, 3, 4, 5, 6, 7);
      }
      #pragma unroll
      for (int rt = 0; rt < 4; ++rt)
        #pragma unroll
        for (int ct = 0; ct < 4; ++ct)
          acc[rt][ct] = __builtin_amdgcn_mfma_f32_16x16x32_f16(
              af[rt], bf[ct], acc[rt][ct], 0, 0, 0);
    }
    __syncthreads();                // all waves done reading A
    if (l < 2) {
      // relu(acc) -> A frags for next layer (col -> next k), swizzle keeps
      // each reg-store on 16 distinct bank pairs (2-way = free).
      #pragma unroll
      for (int ct = 0; ct < 4; ++ct) {
        int kg = wcol + ct * 16 + m;        // next-layer k
        int kt2 = kg >> 5, kl = kg & 31;
        #pragma unroll
        for (int rt = 0; rt < 4; ++rt) {
          #pragma unroll
          for (int r = 0; r < 4; ++r) {
            int m2 = (q * 4 + r) & 15;      // row within tile rt
            *(_Float16*)(AhB + a_off(kt2, rt, m2, kl)) =
                (_Float16)fmaxf(acc[rt][ct][r], 0.f);
          }
        }
      }
    } else {
      #pragma unroll
      for (int rt = 0; rt < 4; ++rt) {
        #pragma unroll
        for (int r = 0; r < 4; ++r) {
          int row = rt * 16 + q * 4 + r;
          int tk = toks[row];
          float wg = wgts[row];
          float* op = out + (size_t)tk * 256 + wcol + m;
          #pragma unroll
          for (int ct = 0; ct < 4; ++ct)
            atomicAdd(op + ct * 16, acc[rt][ct][r] * wg);
        }
      }
    }
  }
}

extern "C" void kernel_launch(void* const* d_in, const int* in_sizes, int n_in,
                              void* d_out, int out_size, void* d_ws, size_t ws_size,
                              hipStream_t stream) {
  const float* feat = (const float*)d_in[0];
  const float* rw1  = (const float*)d_in[1];
  const float* rb1  = (const float*)d_in[2];
  const float* rw2  = (const float*)d_in[3];
  const float* rb2  = (const float*)d_in[4];
  const float* ew1  = (const float*)d_in[5];
  const float* eb1  = (const float*)d_in[6];
  const float* ew2  = (const float*)d_in[7];
  const float* eb2  = (const float*)d_in[8];
  const float* ew3  = (const float*)d_in[9];
  const float* eb3  = (const float*)d_in[10];
  float* out = (float*)d_out;

  char* ws = (char*)d_ws;
  int*      counts = (int*)(ws);
  int*      list   = (int*)(ws + WS_LIST);
  float*    wlist  = (float*)(ws + WS_WLIST);
  _Float16* wt     = (_Float16*)(ws + WS_WT);

  hipMemsetAsync(ws, 0, 256, stream);
  hipMemsetAsync(d_out, 0, (size_t)out_size * sizeof(float), stream);

  convert_w_kernel<<<144, 256, 0, stream>>>(ew1, ew2, ew3, wt);
  router_kernel<<<N_TOK / 32, 128, 0, stream>>>(feat, rw1, rb1, rw2, rb2,
                                                counts, list, wlist);
  expert_kernel<<<dim3(512, E_EXP), 256, 0, stream>>>(
      feat, wt, eb1, eb2, eb3, counts, list, wlist, out);
}